// Round 4
// baseline (5271.260 us; speedup 1.0000x reference)
//
#include <hip/hip_runtime.h>
#include <hip/hip_bf16.h>
#include <hip/hip_fp16.h>

#define NF    15
#define NBF   20
#define TT    1760
#define TS    880
#define EP    64
#define ES    128
#define DF    128
#define H1    384
#define G3    1152
#define INA   896
#define JREP  11

typedef _Float16 h2v __attribute__((ext_vector_type(2)));

__device__ __forceinline__ float sigmf_(float x){ return 1.0f/(1.0f + __expf(-x)); }
__device__ __forceinline__ float tanhf_(float x){ return 2.0f/(1.0f + __expf(-2.0f*x)) - 1.0f; }
__device__ __forceinline__ h2v bc_h2(unsigned u){ return __builtin_bit_cast(h2v, u); }
__device__ __forceinline__ float fdot2_(h2v a, h2v b, float c){
#if __has_builtin(__builtin_amdgcn_fdot2)
  return __builtin_amdgcn_fdot2(a, b, c, false);
#else
  return c + (float)a[0]*(float)b[0] + (float)a[1]*(float)b[1];
#endif
}

// ---------------- frame-rate network: f[64][11][128] ----------------
__global__ __launch_bounds__(128) void k_frame(const float* feat, const int* periods, const float* embp,
   const float* c1w, const float* c1b, const float* c2w, const float* c2b,
   const float* f1w, const float* f1b, const float* f2w, const float* f2b, float* fout)
{
  __shared__ float cat[NF*84];
  __shared__ float x1[13*DF];
  __shared__ float x2[JREP*DF];
  int b = blockIdx.x, tid = threadIdx.x;
  for (int idx = tid; idx < NF*84; idx += 128){
    int j = idx/84, c = idx%84;
    cat[idx] = (c < NBF) ? feat[(b*NF+j)*NBF + c]
                         : embp[periods[b*NF+j]*EP + (c-NBF)];
  }
  __syncthreads();
  int o = tid;
  for (int p = 0; p < 13; ++p){
    float acc = c1b[o];
    for (int kk = 0; kk < 3; ++kk)
      for (int c = 0; c < 84; ++c)
        acc += cat[(p+kk)*84 + c] * c1w[(o*84+c)*3+kk];
    x1[p*DF+o] = tanhf_(acc);
  }
  __syncthreads();
  for (int p = 0; p < JREP; ++p){
    float acc = c2b[o];
    for (int kk = 0; kk < 3; ++kk)
      for (int c = 0; c < DF; ++c)
        acc += x1[(p+kk)*DF+c] * c2w[(o*DF+c)*3+kk];
    x2[p*DF+o] = tanhf_(acc);
  }
  __syncthreads();
  for (int p = 0; p < JREP; ++p){
    float acc = f1b[o];
    for (int c = 0; c < DF; ++c) acc += x2[p*DF+c]*f1w[o*DF+c];
    x1[p*DF+o] = tanhf_(acc);
  }
  __syncthreads();
  for (int p = 0; p < JREP; ++p){
    float acc = f2b[o];
    for (int c = 0; c < DF; ++c) acc += x1[p*DF+c]*f2w[o*DF+c];
    fout[(b*JREP+p)*DF+o] = tanhf_(acc);
  }
}

// ---------------- pack ga_whh f32 -> per-(hf,thread) uint4-contiguous f16 ----------------
// consumed as: block hf, thread tid (r=tid%96, s=tid/96):
//   d_i = wpk4[(hf*18 + i)*768 + tid], i in [0,18)
//   dword gd = i*4+c : q=gd/6, k6=gd%6, g=k6>>1, hsel=k6&1
//   jbase = ((hf ^ (s>>1))*2 + (s&1))*48 ; half u: j = jbase + 4q + 2*hsel + u ; row i = hf*96 + r
__global__ __launch_bounds__(256) void k_wpack3(const float* whh, _Float16* wpk){
  int o = blockIdx.x*256 + threadIdx.x;        // < 442368
  int u  = o & 1;
  int c  = (o >> 1) & 3;
  int idx = o >> 3;                            // uint4 index
  int tid = idx % 768;
  int i18 = (idx / 768) % 18;
  int hf  = idx / (768*18);
  int r = tid % 96, s = tid / 96;
  int gd = i18*4 + c;
  int q = gd / 6, k6 = gd % 6;
  int g = k6 >> 1, hsel = k6 & 1;
  int jbase = ((hf ^ (s >> 1))*2 + (s & 1))*48;
  int j = jbase + 4*q + 2*hsel + u;
  int i = hf*96 + r;
  wpk[o] = (_Float16)whh[(g*H1 + i)*H1 + j];
}

// ---------------- GA tables: GA[k][256][1152] ----------------
__global__ __launch_bounds__(256) void k_tables(const float* wih, const float* emb, float* GA){
  __shared__ float Wl[64*129];
  int k = blockIdx.x/18, g0 = (blockIdx.x%18)*64;
  int tid = threadIdx.x;
  for (int idx = tid; idx < 64*128; idx += 256){
    int gg = idx>>7, c = idx&127;
    Wl[gg*129+c] = wih[(size_t)(g0+gg)*INA + k*128 + c];
  }
  __syncthreads();
  int vv = tid>>6, gg = tid&63;
  for (int v = vv; v < 256; v += 4){
    const float* e = emb + (size_t)v*ES;
    float acc = 0.f;
    for (int c = 0; c < 128; ++c) acc += e[c]*Wl[gg*129+c];
    GA[(size_t)(k*256+v)*G3 + g0+gg] = acc;
  }
}

// ---------------- xWrepA[b][j][1152] ----------------
__global__ __launch_bounds__(256) void k_xwrepA(const float* wih, const float* f,
                                                const float* bih, const float* bhh, float* xwA){
  __shared__ float Wl[64*129];
  int g0 = blockIdx.x*64, tid = threadIdx.x;
  for (int idx = tid; idx < 64*128; idx += 256){
    int gg = idx>>7, c = idx&127;
    Wl[gg*129+c] = wih[(size_t)(g0+gg)*INA + 768 + c];
  }
  __syncthreads();
  int vv = tid>>6, gg = tid&63; int g = g0+gg;
  float badd = bih[g] + (g < 768 ? bhh[g] : 0.f);
  for (int row = vv; row < 64*JREP; row += 4){
    const float* fr = f + (size_t)row*DF;
    float acc = badd;
    for (int c = 0; c < 128; ++c) acc += fr[c]*Wl[gg*129+c];
    xwA[(size_t)row*G3 + g] = acc;
  }
}

// ---------------- xWrepB[b][j][48] ----------------
__global__ __launch_bounds__(256) void k_xwrepB(const float* wih, const float* f,
                                                const float* bih, const float* bhh, float* xwB){
  __shared__ float Wl[48*129];
  int b = blockIdx.x, tid = threadIdx.x;
  for (int idx = tid; idx < 48*128; idx += 256){
    int r = idx>>7, c = idx&127;
    Wl[r*129+c] = wih[r*512 + 384 + c];
  }
  __syncthreads();
  for (int idx = tid; idx < JREP*48; idx += 256){
    int j = idx/48, r = idx%48;
    const float* fr = f + (size_t)(b*JREP+j)*DF;
    float acc = bih[r] + (r < 32 ? bhh[r] : 0.f);
    for (int c = 0; c < 128; ++c) acc += fr[c]*Wl[r*129+c];
    xwB[(size_t)(b*JREP+j)*48 + r] = acc;
  }
}

// ---------------- md2 embed tables: T2[tbl][256][256] ----------------
__global__ __launch_bounds__(256) void k_t2(const float* w1, const float* w2, const float* emb, float* T2){
  __shared__ float Wl[64*129];
  int tbl = blockIdx.x>>2; int c0 = (blockIdx.x&3)*64; int tid = threadIdx.x;
  const float* w = tbl ? w2 : w1;
  for (int idx = tid; idx < 64*128; idx += 256){
    int cc = idx>>7, e = idx&127;
    Wl[cc*129+e] = w[(c0+cc)*144 + 16 + e];
  }
  __syncthreads();
  int vv = tid>>6, cc = tid&63;
  for (int v = vv; v < 256; v += 4){
    const float* e = emb + (size_t)v*ES;
    float acc = 0.f;
    for (int c = 0; c < 128; ++c) acc += e[c]*Wl[cc*129+c];
    T2[tbl*65536 + v*256 + c0+cc] = acc;
  }
}

// ---------------- GRU-A weight-stationary scan v4: 4 blocks per batch, 2 barriers/step ----------------
#define LD18(n) uint4 d##n = wsrc[(size_t)(n)*768];
#define Q2(A,B,C, q2) { \
  h2v hA = bc_h2(hv##q2), hB = bc_h2(hw##q2); \
  ar = fdot2_(hA, bc_h2(A.x), ar); ar = fdot2_(hB, bc_h2(A.y), ar); \
  az = fdot2_(hA, bc_h2(A.z), az); az = fdot2_(hB, bc_h2(A.w), az); \
  an = fdot2_(hA, bc_h2(B.x), an); an = fdot2_(hB, bc_h2(B.y), an); \
  h2v hC = bc_h2(hx##q2), hD = bc_h2(hy##q2); \
  ar = fdot2_(hC, bc_h2(B.z), ar); ar = fdot2_(hD, bc_h2(B.w), ar); \
  az = fdot2_(hC, bc_h2(C.x), az); az = fdot2_(hD, bc_h2(C.y), az); \
  an = fdot2_(hC, bc_h2(C.z), an); an = fdot2_(hD, bc_h2(C.w), an); }
#define DOTS12 \
  Q2(d0,d1,d2,0) Q2(d3,d4,d5,1) Q2(d6,d7,d8,2) \
  Q2(d9,d10,d11,3) Q2(d12,d13,d14,4) Q2(d15,d16,d17,5)

__global__ __launch_bounds__(768, 3) void k_scanA4(const int* __restrict__ in_data,
        const float* __restrict__ GA, const float* __restrict__ xwA,
        const uint4* __restrict__ wpk, const float* __restrict__ bhh,
        unsigned* __restrict__ g1u, unsigned* hx, int* flags)
{
  __shared__ __align__(16) unsigned h16u[48];        // own-quarter h (u32 = 2 f16 rows)
  __shared__ __align__(8)  float pg[3][8][96];       // partials [gate][grp][row]
  __shared__ __align__(8)  float part[2][2][3][96];  // xW partials [buf][crew][gate][row]
  __shared__ int indr[2][8];
  const int P = blockIdx.x;
  const int b = P & 63, hf = P >> 6;
  const int tid = threadIdx.x;
  const int r = tid % 96, grp = tid / 96;
  const int qq = grp >> 1, par = grp & 1;
  const int qt = hf ^ qq;                      // h-quarter this thread consumes
  const int* ind_b = in_data + (size_t)b*TT*3;

  // weights: 18 uint4, loaded once (same wpk3 layout; grp == old s)
  const uint4* wsrc = wpk + (size_t)(hf*18)*768 + tid;
  LD18(0) LD18(1) LD18(2) LD18(3) LD18(4) LD18(5) LD18(6) LD18(7) LD18(8)
  LD18(9) LD18(10) LD18(11) LD18(12) LD18(13) LD18(14) LD18(15) LD18(16) LD18(17)

  const bool isA = (tid >= 192 && tid < 480);
  const bool isB = (tid >= 480);
  const int  cc  = isA ? (tid-192) : (tid-480);
  const int  col = (cc/96)*H1 + hf*96 + (cc%96);

  float hreg0 = 0.f, hreg1 = 0.f, bn0 = 0.f, bn1 = 0.f;
  if (tid < 48){
    bn0 = bhh[768 + hf*96 + 2*tid];
    bn1 = bhh[768 + hf*96 + 2*tid + 1];
    h16u[tid] = 0u;
  }
  // prologue: xW parts for t=0 ; indices for t=1
  if (isA){
    float a0 = GA[((size_t)0*256 + ind_b[0])*G3 + col];
    float a1 = GA[((size_t)1*256 + ind_b[1])*G3 + col];
    float a2 = GA[((size_t)2*256 + ind_b[2])*G3 + col];
    part[0][0][cc/96][cc%96] = a0+a1+a2;
  } else if (isB){
    float a0 = GA[((size_t)3*256 + ind_b[3])*G3 + col];
    float a1 = GA[((size_t)4*256 + ind_b[4])*G3 + col];
    float a2 = GA[((size_t)5*256 + ind_b[5])*G3 + col];
    float a3 = xwA[((size_t)b*JREP + 0)*G3 + col];
    part[0][1][cc/96][cc%96] = a0+a1+a2+a3;
  }
  if (tid >= 192 && tid < 198) indr[1][tid-192] = ind_b[6 + (tid-192)];

  int* flgp = flags + (b*4 + qt)*32;           // partner (or own) flag
  const unsigned* hxq = hx + ((size_t)(b*4 + qt)*2)*48 + par*24;
  unsigned* hxo = hx + ((size_t)(b*4 + hf)*2)*48;
  int* flgo = flags + (b*4 + hf)*32;
  __syncthreads();

  for (int t = 0; t < TS; ++t){
    const int nb = t & 1;
    // ---- acquire h source into 24 u32 regs ----
    unsigned hv0,hw0,hx0,hy0, hv1,hw1,hx1,hy1, hv2,hw2,hx2,hy2;
    unsigned hv3,hw3,hx3,hy3, hv4,hw4,hx4,hy4, hv5,hw5,hx5,hy5;
    if (qq == 0){
      const uint4* hp = (const uint4*)&h16u[par*24];
      uint4 a = hp[0], bq = hp[1], c2 = hp[2], dd = hp[3], e = hp[4], f = hp[5];
      hv0=a.x; hw0=a.y; hx0=a.z; hy0=a.w;
      hv1=bq.x;hw1=bq.y;hx1=bq.z;hy1=bq.w;
      hv2=c2.x;hw2=c2.y;hx2=c2.z;hy2=c2.w;
      hv3=dd.x;hw3=dd.y;hx3=dd.z;hy3=dd.w;
      hv4=e.x; hw4=e.y; hx4=e.z; hy4=e.w;
      hv5=f.x; hw5=f.y; hx5=f.z; hy5=f.w;
    } else {
      while (__hip_atomic_load(flgp, __ATOMIC_RELAXED, __HIP_MEMORY_SCOPE_AGENT) < t)
        __builtin_amdgcn_s_sleep(1);
      __builtin_amdgcn_sched_barrier(0);
      const unsigned* hp = hxq + (size_t)((t+1)&1)*48;
      hv0=__hip_atomic_load(hp+ 0,__ATOMIC_RELAXED,__HIP_MEMORY_SCOPE_AGENT);
      hw0=__hip_atomic_load(hp+ 1,__ATOMIC_RELAXED,__HIP_MEMORY_SCOPE_AGENT);
      hx0=__hip_atomic_load(hp+ 2,__ATOMIC_RELAXED,__HIP_MEMORY_SCOPE_AGENT);
      hy0=__hip_atomic_load(hp+ 3,__ATOMIC_RELAXED,__HIP_MEMORY_SCOPE_AGENT);
      hv1=__hip_atomic_load(hp+ 4,__ATOMIC_RELAXED,__HIP_MEMORY_SCOPE_AGENT);
      hw1=__hip_atomic_load(hp+ 5,__ATOMIC_RELAXED,__HIP_MEMORY_SCOPE_AGENT);
      hx1=__hip_atomic_load(hp+ 6,__ATOMIC_RELAXED,__HIP_MEMORY_SCOPE_AGENT);
      hy1=__hip_atomic_load(hp+ 7,__ATOMIC_RELAXED,__HIP_MEMORY_SCOPE_AGENT);
      hv2=__hip_atomic_load(hp+ 8,__ATOMIC_RELAXED,__HIP_MEMORY_SCOPE_AGENT);
      hw2=__hip_atomic_load(hp+ 9,__ATOMIC_RELAXED,__HIP_MEMORY_SCOPE_AGENT);
      hx2=__hip_atomic_load(hp+10,__ATOMIC_RELAXED,__HIP_MEMORY_SCOPE_AGENT);
      hy2=__hip_atomic_load(hp+11,__ATOMIC_RELAXED,__HIP_MEMORY_SCOPE_AGENT);
      hv3=__hip_atomic_load(hp+12,__ATOMIC_RELAXED,__HIP_MEMORY_SCOPE_AGENT);
      hw3=__hip_atomic_load(hp+13,__ATOMIC_RELAXED,__HIP_MEMORY_SCOPE_AGENT);
      hx3=__hip_atomic_load(hp+14,__ATOMIC_RELAXED,__HIP_MEMORY_SCOPE_AGENT);
      hy3=__hip_atomic_load(hp+15,__ATOMIC_RELAXED,__HIP_MEMORY_SCOPE_AGENT);
      hv4=__hip_atomic_load(hp+16,__ATOMIC_RELAXED,__HIP_MEMORY_SCOPE_AGENT);
      hw4=__hip_atomic_load(hp+17,__ATOMIC_RELAXED,__HIP_MEMORY_SCOPE_AGENT);
      hx4=__hip_atomic_load(hp+18,__ATOMIC_RELAXED,__HIP_MEMORY_SCOPE_AGENT);
      hy4=__hip_atomic_load(hp+19,__ATOMIC_RELAXED,__HIP_MEMORY_SCOPE_AGENT);
      hv5=__hip_atomic_load(hp+20,__ATOMIC_RELAXED,__HIP_MEMORY_SCOPE_AGENT);
      hw5=__hip_atomic_load(hp+21,__ATOMIC_RELAXED,__HIP_MEMORY_SCOPE_AGENT);
      hx5=__hip_atomic_load(hp+22,__ATOMIC_RELAXED,__HIP_MEMORY_SCOPE_AGENT);
      hy5=__hip_atomic_load(hp+23,__ATOMIC_RELAXED,__HIP_MEMORY_SCOPE_AGENT);
    }
    // ---- crews: issue gathers for t+1 (values used after dots) ----
    const int tp = t + 1;
    float gv0=0.f, gv1=0.f, gv2=0.f, gv3=0.f;
    if (tp < TS){
      if (isA){
        gv0 = GA[((size_t)0*256 + indr[tp&1][0])*G3 + col];
        gv1 = GA[((size_t)1*256 + indr[tp&1][1])*G3 + col];
        gv2 = GA[((size_t)2*256 + indr[tp&1][2])*G3 + col];
      } else if (isB){
        gv0 = GA[((size_t)3*256 + indr[tp&1][3])*G3 + col];
        gv1 = GA[((size_t)4*256 + indr[tp&1][4])*G3 + col];
        gv2 = GA[((size_t)5*256 + indr[tp&1][5])*G3 + col];
        gv3 = xwA[((size_t)b*JREP + tp/80)*G3 + col];
      }
    }
    int iv = 0;
    const int stg = t + 2;
    const bool doStg = (tid >= 192 && tid < 198 && stg < TS);
    if (doStg) iv = ind_b[6*stg + (tid-192)];
    // ---- dots ----
    float ar=0.f, az=0.f, an=0.f;
    DOTS12
    pg[0][grp][r] = ar; pg[1][grp][r] = az; pg[2][grp][r] = an;
    // ---- crews finalize ----
    if (tp < TS){
      if (isA)      part[tp&1][0][cc/96][cc%96] = gv0+gv1+gv2;
      else if (isB) part[tp&1][1][cc/96][cc%96] = gv0+gv1+gv2+gv3;
    }
    if (doStg) indr[t&1][tid-192] = iv;
    __syncthreads();
    // ---- epilogue: wave 0, 48 lanes, 2 rows each ----
    if (tid < 48){
      float R = 0.f, Z = 0.f, Gn = 0.f, R1 = 0.f, Z1 = 0.f, Gn1 = 0.f;
      #pragma unroll
      for (int gp = 0; gp < 8; ++gp){
        float2 p0 = *(const float2*)&pg[0][gp][2*tid];
        float2 p1 = *(const float2*)&pg[1][gp][2*tid];
        float2 p2 = *(const float2*)&pg[2][gp][2*tid];
        R += p0.x; R1 += p0.y; Z += p1.x; Z1 += p1.y; Gn += p2.x; Gn1 += p2.y;
      }
      float2 xa0 = *(const float2*)&part[nb][0][0][2*tid];
      float2 xa1 = *(const float2*)&part[nb][0][1][2*tid];
      float2 xa2 = *(const float2*)&part[nb][0][2][2*tid];
      float2 xb0 = *(const float2*)&part[nb][1][0][2*tid];
      float2 xb1 = *(const float2*)&part[nb][1][1][2*tid];
      float2 xb2 = *(const float2*)&part[nb][1][2][2*tid];
      float rr0 = sigmf_(R  + xa0.x + xb0.x);
      float zz0 = sigmf_(Z  + xa1.x + xb1.x);
      float nn0 = tanhf_(xa2.x + xb2.x + rr0*(Gn + bn0));
      float h0 = (1.f - zz0)*nn0 + zz0*hreg0; hreg0 = h0;
      float rr1 = sigmf_(R1 + xa0.y + xb0.y);
      float zz1 = sigmf_(Z1 + xa1.y + xb1.y);
      float nn1 = tanhf_(xa2.y + xb2.y + rr1*(Gn1 + bn1));
      float h1 = (1.f - zz1)*nn1 + zz1*hreg1; hreg1 = h1;
      unsigned pack = (unsigned)__builtin_bit_cast(unsigned short, (_Float16)h0)
                    | ((unsigned)__builtin_bit_cast(unsigned short, (_Float16)h1) << 16);
      h16u[tid] = pack;
      g1u[((size_t)b*TS + t)*192 + hf*48 + tid] = pack;
      __hip_atomic_store(hxo + (size_t)nb*48 + tid, pack,
                         __ATOMIC_RELAXED, __HIP_MEMORY_SCOPE_AGENT);
      if (tid == 0)
        __hip_atomic_store(flgo, t+1, __ATOMIC_RELEASE, __HIP_MEMORY_SCOPE_AGENT);
    }
    __syncthreads();
  }
}

// ---------------- xW_B = g1 @ gb_wih[:, :384].T + xWrepB ----------------
__global__ __launch_bounds__(256) void k_xwB(const _Float16* g1, const float* wih,
                                             const float* xwrB, float* xwB){
  __shared__ _Float16 gl[16*392];
  int bi = blockIdx.x; int b = bi/55; int t0 = (bi%55)*16; int tid = threadIdx.x;
  for (int idx = tid; idx < 16*H1; idx += 256){
    int tt = idx/H1, c = idx%H1;
    gl[tt*392+c] = g1[((size_t)b*TS + t0+tt)*H1 + c];
  }
  __syncthreads();
  int rr = tid>>4, tt = tid&15;
  int t = t0+tt;
  const float* xr = xwrB + ((size_t)(b*JREP) + t/80)*48;
  for (int rb = 0; rb < 3; ++rb){
    int r = rb*16 + rr;
    const float* wrow = wih + (size_t)r*512;
    float acc = 0.f;
    for (int c = 0; c < H1; ++c) acc += (float)gl[tt*392+c]*wrow[c];
    xwB[((size_t)b*TS + t)*48 + r] = acc + xr[r];
  }
}

// ---------------- GRU-B scan (tiny) ----------------
__global__ __launch_bounds__(64) void k_scanB(const float* xwB, const float* whh,
                                              const float* bhh, float* g2){
  __shared__ float wl[48*17];
  __shared__ float h2s[16];
  __shared__ float pre[32];
  __shared__ float xn[16], gn[16];
  int b = blockIdx.x, tid = threadIdx.x;
  for (int idx = tid; idx < 768; idx += 64) wl[(idx>>4)*17 + (idx&15)] = whh[idx];
  if (tid < 16) h2s[tid] = 0.f;
  float bn = (tid >= 32 && tid < 48) ? bhh[tid] : 0.f;
  __syncthreads();
  for (int t = 0; t < TS; ++t){
    if (tid < 48){
      float xw = xwB[((size_t)b*TS + t)*48 + tid];
      float gh = 0.f;
      for (int e = 0; e < 16; ++e) gh += wl[tid*17+e]*h2s[e];
      if (tid < 32) pre[tid] = xw + gh;
      else { xn[tid-32] = xw; gn[tid-32] = gh + bn; }
    }
    __syncthreads();
    if (tid < 16){
      float r = sigmf_(pre[tid]), z = sigmf_(pre[16+tid]);
      float n = tanhf_(xn[tid] + r*gn[tid]);
      float hn = (1.f - z)*n + z*h2s[tid];
      h2s[tid] = hn;
      g2[((size_t)b*TS + t)*16 + tid] = hn;
    }
    __syncthreads();
  }
}

// ---------------- mdense + output interleave ----------------
__global__ __launch_bounds__(256) void k_out(const float* g2, const int* targets, const float* T2,
    const float* m1w1, const float* m1w2, const float* m1b1, const float* m1b2,
    const float* m1f1, const float* m1f2,
    const float* m2w1, const float* m2w2, const float* m2b1, const float* m2b2,
    const float* m2f1, const float* m2f2, float* out)
{
  __shared__ float wA[256*17], wB[256*17], wC[256*17], wD[256*17];
  __shared__ float g2l[16*16];
  int bi = blockIdx.x; int b = bi/55; int t0 = (bi%55)*16; int c = threadIdx.x;
  for (int d = 0; d < 16; ++d){
    wA[c*17+d] = m1w1[c*16+d];  wB[c*17+d] = m1w2[c*16+d];
    wC[c*17+d] = m2w1[c*144+d]; wD[c*17+d] = m2w2[c*144+d];
  }
  { int tt = c>>4, d = c&15; g2l[c] = g2[((size_t)b*TS + t0+tt)*16 + d]; }
  __syncthreads();
  float b1a = m1b1[c], b2a = m1b2[c], f1a = m1f1[c], f2a = m1f2[c];
  float b1b = m2b1[c], b2b = m2b2[c], f1b = m2f1[c], f2b = m2f2[c];
  for (int tt = 0; tt < 16; ++tt){
    int t = t0+tt;
    float d1 = b1a, d2 = b2a, e1 = b1b, e2 = b2b;
    for (int d = 0; d < 16; ++d){
      float g = g2l[tt*16+d];
      d1 += g*wA[c*17+d]; d2 += g*wB[c*17+d];
      e1 += g*wC[c*17+d]; e2 += g*wD[c*17+d];
    }
    int v = targets[b*TT + 2*t];
    e1 += T2[v*256+c]; e2 += T2[65536 + v*256+c];
    float o1 = f1a*tanhf_(d1) + f2a*tanhf_(d2);
    float o2 = f1b*tanhf_(e1) + f2b*tanhf_(e2);
    size_t base = ((size_t)b*TS + t)*2*256;
    out[base + c]       = o1;
    out[base + 256 + c] = o2;
  }
}

extern "C" void kernel_launch(void* const* d_in, const int* in_sizes, int n_in,
                              void* d_out, int out_size, void* d_ws, size_t ws_size,
                              hipStream_t stream) {
  const int*   in_data = (const int*)  d_in[0];
  const float* feat    = (const float*)d_in[1];
  const int*   periods = (const int*)  d_in[2];
  const int*   targets = (const int*)  d_in[3];
  const float* embp    = (const float*)d_in[4];
  const float* embs    = (const float*)d_in[5];
  const float* c1w = (const float*)d_in[6];  const float* c1b = (const float*)d_in[7];
  const float* c2w = (const float*)d_in[8];  const float* c2b = (const float*)d_in[9];
  const float* f1w = (const float*)d_in[10]; const float* f1b = (const float*)d_in[11];
  const float* f2w = (const float*)d_in[12]; const float* f2b = (const float*)d_in[13];
  const float* ga_wih = (const float*)d_in[14]; const float* ga_whh = (const float*)d_in[15];
  const float* ga_bih = (const float*)d_in[16]; const float* ga_bhh = (const float*)d_in[17];
  const float* gb_wih = (const float*)d_in[18]; const float* gb_whh = (const float*)d_in[19];
  const float* gb_bih = (const float*)d_in[20]; const float* gb_bhh = (const float*)d_in[21];
  const float* m1w1 = (const float*)d_in[22]; const float* m1w2 = (const float*)d_in[23];
  const float* m1b1 = (const float*)d_in[24]; const float* m1b2 = (const float*)d_in[25];
  const float* m1f1 = (const float*)d_in[26]; const float* m1f2 = (const float*)d_in[27];
  const float* m2w1 = (const float*)d_in[28]; const float* m2w2 = (const float*)d_in[29];
  const float* m2b1 = (const float*)d_in[30]; const float* m2b2 = (const float*)d_in[31];
  const float* m2f1 = (const float*)d_in[32]; const float* m2f2 = (const float*)d_in[33];
  float* out = (float*)d_out;

  // workspace layout (floats)
  float* GA     = (float*)d_ws;                  // 6*256*1152     = 1,769,472
  float* xWrepA = GA     + 1769472;              // 704*1152       =   811,008
  float* xWrepB = xWrepA + 811008;               // 704*48         =    33,792
  float* fbuf   = xWrepB + 33792;                // 704*128        =    90,112
  float* xWB    = fbuf   + 90112;                // 56320*48       = 2,703,360
  float* g2buf  = xWB    + 2703360;              // 56320*16       =   901,120
  float* T2     = g2buf  + 901120;               // 2*256*256      =   131,072
  _Float16* Wpk = (_Float16*)(T2 + 131072);      // 442,368 halves
  unsigned* hx  = (unsigned*)(Wpk + 442368);     // 64*4*2*48 u32  =    24,576
  int*  flags   = (int*)(hx + 24576);            // 256*32 ints (128B padded)
  _Float16* g1  = (_Float16*)d_out;              // scratch inside output buffer (43.3MB < 115MB)

  hipMemsetAsync(flags, 0, 256*32*sizeof(int), stream);
  hipMemsetAsync(hx, 0, 24576*sizeof(unsigned), stream);
  hipLaunchKernelGGL(k_frame, dim3(64), dim3(128), 0, stream,
                     feat, periods, embp, c1w, c1b, c2w, c2b, f1w, f1b, f2w, f2b, fbuf);
  hipLaunchKernelGGL(k_wpack3, dim3(1728), dim3(256), 0, stream, ga_whh, Wpk);
  hipLaunchKernelGGL(k_tables, dim3(108), dim3(256), 0, stream, ga_wih, embs, GA);
  hipLaunchKernelGGL(k_t2, dim3(8), dim3(256), 0, stream, m2w1, m2w2, embs, T2);
  hipLaunchKernelGGL(k_xwrepA, dim3(18), dim3(256), 0, stream, ga_wih, fbuf, ga_bih, ga_bhh, xWrepA);
  hipLaunchKernelGGL(k_xwrepB, dim3(64), dim3(256), 0, stream, gb_wih, fbuf, gb_bih, gb_bhh, xWrepB);
  hipLaunchKernelGGL(k_scanA4, dim3(256), dim3(768), 0, stream,
                     in_data, GA, xWrepA, (const uint4*)Wpk, ga_bhh,
                     (unsigned*)g1, hx, flags);
  hipLaunchKernelGGL(k_xwB, dim3(64*55), dim3(256), 0, stream, g1, gb_wih, xWrepB, xWB);
  hipLaunchKernelGGL(k_scanB, dim3(64), dim3(64), 0, stream, xWB, gb_whh, gb_bhh, g2buf);
  hipLaunchKernelGGL(k_out, dim3(64*55), dim3(256), 0, stream,
                     g2buf, targets, T2, m1w1, m1w2, m1b1, m1b2, m1f1, m1f2,
                     m2w1, m2w2, m2b1, m2b2, m2f1, m2f2, out);
}